// Round 4
// baseline (594.758 us; speedup 1.0000x reference)
//
#include <hip/hip_runtime.h>

// 2x nearest-neighbor upsample: x[16,128,128,128] f32 -> out[16,128,256,256].
// Each thread: nt-load 2 input cols, store (a,a,b,b) float4 into output
// rows 2h and 2h+1. Per wave: load = 512 B contiguous, each store = 1 KiB
// contiguous. Minimal HBM traffic: 128 MiB read + 512 MiB write, once.
//
// R4: FINAL — revert of the R3 measurement probe back to the R1 kernel
// (session best, 593.0 us). Session evidence trail:
//   R0 nt-stores        594.4 us
//   R1 plain stores     593.0 us   <- this kernel
//   R2 batch-8 MLP      623.4 us   (only variant that poked out of the
//                                   harness window -> regression)
//   R3 4x-body probe    594.4 us   (4x instructions+touched bytes = +1 us!)
// R3 proved the kernel is NOT on the timed graph's critical path: dur_us
// floor (~594 us) is the harness reset chain (2.147 GB poison fills @
// ~6.3 TB/s, themselves at HBM roofline). Kernel ideal = 671 MB @ 6.3 TB/s
// ~= 106 us, fully hidden. Store cache-mode (R0 vs R1) is a null variable;
// keep plain stores (marginally best measured) and nt loads (read-once).

typedef float v2f __attribute__((ext_vector_type(2)));
typedef float v4f __attribute__((ext_vector_type(4)));

__global__ __launch_bounds__(256) void upsample_57312043598151_kernel(
    const v2f* __restrict__ in, v4f* __restrict__ out) {
    const int tid = blockIdx.x * blockDim.x + threadIdx.x;  // [0, 16777216)

    const v2f v = __builtin_nontemporal_load(&in[tid]);

    const int col2 = tid & 63;   // float2 index within the input row (W=128 -> 64)
    const int r    = tid >> 6;   // flattened (b, c, h) input row index
    const int h    = r & 127;    // input H coordinate
    const int bc   = r >> 7;     // flattened (b, c)

    const int out_row0 = bc * 256 + (h << 1);  // output row (H_out = 256)

    v4f o;
    o.x = v.x; o.y = v.x; o.z = v.y; o.w = v.y;

    const int idx = out_row0 * 64 + col2;  // float4 index (out row = 64 float4)
    out[idx]      = o;  // row 2h
    out[idx + 64] = o;  // row 2h+1
}

extern "C" void kernel_launch(void* const* d_in, const int* in_sizes, int n_in,
                              void* d_out, int out_size, void* d_ws, size_t ws_size,
                              hipStream_t stream) {
    const v2f* in = (const v2f*)d_in[0];
    v4f* out = (v4f*)d_out;

    const int n = in_sizes[0];          // 33,554,432 floats
    const int n_threads = n / 2;        // one thread per float2 = 16,777,216
    const int block = 256;
    const int grid = n_threads / block; // 65,536

    upsample_57312043598151_kernel<<<grid, block, 0, stream>>>(in, out);
}